// Round 7
// baseline (468.727 us; speedup 1.0000x reference)
//
#include <hip/hip_runtime.h>
#include <hip/hip_bf16.h>
#include <math.h>

#ifndef M_PI
#define M_PI 3.14159265358979323846
#endif

// Problem constants
#define NN 10000      // nodes
#define NE 160000     // edges
#define NC 16         // channels
#define NQ 5          // 2*order+1
#define NFR 10        // N_FREQ * N_RINGS
#define CQ 80         // NC*NQ
#define OP 80         // outputs per node
#define KTOT 800      // GEMM K
#define WSZ 64000     // 80*800 weight elements

typedef __attribute__((ext_vector_type(8))) short bf16x8;
typedef __attribute__((ext_vector_type(4))) float f32x4;
typedef __attribute__((ext_vector_type(4))) unsigned u32x4;

// exact RNE float->bf16 (finite inputs)
static __device__ __forceinline__ unsigned f2bf_u(float f) {
    unsigned u = __float_as_uint(f);
    return (u + 0x7fffu + ((u >> 16) & 1u)) >> 16;
}
static __device__ __forceinline__ unsigned pack2bf(float lo, float hi) {
    unsigned uh = __float_as_uint(hi);
    uh = (uh + 0x7fffu + ((uh >> 16) & 1u)) & 0xffff0000u;
    return f2bf_u(lo) | uh;
}

// ---------------------------------------------------------------------------
// Reorder + convert: W[o,c,p,q,f,r] fp32 -> Wt[n][klog] bf16 where
// n = o*5+p,  klog = 200*quad + 20*fr + ii,  cq = 20*quad + ii,  fr = f*2+r.
// This k-permutation lets each MFMA lane (quad,lrow) generate its A-fragment
// from register-resident xt[ii]*tv[fr] with compile-time indices.
// (Mapping spot-verified element-wise against W's [o,c,p,q,f,r] strides.)
// ---------------------------------------------------------------------------
__global__ void reorder_wt(const float* __restrict__ W1, const float* __restrict__ W2,
                           unsigned short* __restrict__ Wt1, unsigned short* __restrict__ Wt2) {
    int i = blockIdx.x * blockDim.x + threadIdx.x;  // over 64000
    if (i >= WSZ) return;
    int n = i / KTOT;
    int klog = i % KTOT;
    int quad = klog / 200;
    int rem  = klog % 200;
    int fr = rem / 20, ii = rem % 20;
    int cq = 20 * quad + ii;
    int c = cq / NQ, q = cq % NQ;
    int f = fr / 2,  r = fr % 2;
    int o = n / NQ,  p = n % NQ;
    int src = ((((o * NC + c) * NQ + p) * NQ + q) * 5 + f) * 2 + r;
    Wt1[i] = (unsigned short)f2bf_u(W1[src]);
    Wt2[i] = (unsigned short)f2bf_u(W2[src]);
}

// ---------------------------------------------------------------------------
// Self-interaction + bias (fp32): y[n,op] = sum_cq x[n,cq]*Ws[o,c,p,q] + (p==0)b[o]
// Full write — serves as init before edge atomics.
// ---------------------------------------------------------------------------
__global__ void selfint(const float* __restrict__ xin, const float* __restrict__ Ws,
                        const float* __restrict__ b, float* __restrict__ y) {
    __shared__ float ws_s[NC * NC * NQ * NQ];  // 25.6 KB
    int tid = threadIdx.x;
    for (int i = tid; i < NC * NC * NQ * NQ; i += blockDim.x) ws_s[i] = Ws[i];
    __syncthreads();
    int idx = blockIdx.x * blockDim.x + tid;     // over N*80
    if (idx >= NN * OP) return;
    int n = idx / OP, op = idx % OP;
    int o = op / NQ, p = op % NQ;
    const float* xrow = xin + n * CQ;
    float acc = (p == 0) ? b[o] : 0.0f;
    #pragma unroll
    for (int c = 0; c < NC; ++c)
        #pragma unroll
        for (int q = 0; q < NQ; ++q)
            acc = fmaf(xrow[c * NQ + q], ws_s[o * 400 + c * 25 + p * 5 + q], acc);
    y[idx] = acc;
}

// ---------------------------------------------------------------------------
// Edge conv v6: zero-LDS MFMA GEMM, differential fix of R6's failure.
// One wave per block, 16 edges. Lane (quad,lrow) owns edge blk*16+lrow,
// cq-range [20*quad,20*quad+20). A-fragment for K-step ks generated in regs:
//   a[j] = bf16( xt[(8ks+j)%20] * tv[(8ks+j)/20] ),  klog = 200*quad+8ks+j
// matching Wt's k-permutation. B-fragment: dwordx4 from L2-hot Wt (128 KB).
// Changes vs failed R6: (1) __builtin_bit_cast instead of union type-pun,
// (2) dst re-read from ei[] in epilogue instead of __shfl, (3)
// __launch_bounds__(64,2) instead of (64,4) to remove VGPR-cap spill pressure.
// ---------------------------------------------------------------------------
__global__ __launch_bounds__(64, 2)
void edge_conv_mfma(const float* __restrict__ xin, const int* __restrict__ ei,
                    const float* __restrict__ pre, const float* __restrict__ phi_arr,
                    const unsigned short* __restrict__ Wt, float* __restrict__ y) {
    const int lane = threadIdx.x;
    const int lrow = lane & 15;
    const int quad = lane >> 4;
    const int e0 = blockIdx.x * 16;     // NE = 10000 * 16 exactly
    const int e  = e0 + lrow;

    const int src = ei[2 * e];
    float s1, c1;
    sincosf(phi_arr[e], &s1, &c1);
    const float c2 = c1 * c1 - s1 * s1;
    const float s2 = 2.0f * c1 * s1;

    // 20 features (4 channels) of the transported source row, quarter = quad
    float xt[20];
    {
        const float4* xp = (const float4*)(xin + (size_t)src * CQ + 20 * quad);
        #pragma unroll
        for (int k4 = 0; k4 < 5; ++k4) {
            float4 v = xp[k4];
            xt[4 * k4 + 0] = v.x; xt[4 * k4 + 1] = v.y;
            xt[4 * k4 + 2] = v.z; xt[4 * k4 + 3] = v.w;
        }
        #pragma unroll
        for (int cc = 0; cc < 4; ++cc) {
            float a1 = xt[cc * 5 + 1], b1 = xt[cc * 5 + 2];
            float a2 = xt[cc * 5 + 3], b2 = xt[cc * 5 + 4];
            xt[cc * 5 + 1] = c1 * a1 - s1 * b1;
            xt[cc * 5 + 2] = s1 * a1 + c1 * b1;
            xt[cc * 5 + 3] = c2 * a2 - s2 * b2;
            xt[cc * 5 + 4] = s2 * a2 + c2 * b2;
        }
    }
    float tv[NFR];
    #pragma unroll
    for (int fr = 0; fr < NFR; ++fr) tv[fr] = pre[(size_t)e * NFR + fr];

    f32x4 acc[5];
    #pragma unroll
    for (int nt = 0; nt < 5; ++nt) acc[nt] = (f32x4){0.f, 0.f, 0.f, 0.f};

    // 5 B row bases (n = 16*nt + lrow), each offset to this quad's 200-column
    const unsigned short* wb[5];
    #pragma unroll
    for (int nt = 0; nt < 5; ++nt)
        wb[nt] = Wt + (size_t)(16 * nt + lrow) * KTOT + 200 * quad;

    #pragma unroll
    for (int ks = 0; ks < 25; ++ks) {
        u32x4 aw;
        #pragma unroll
        for (int jp = 0; jp < 4; ++jp) {
            const int k0 = 8 * ks + 2 * jp;
            const int k1 = k0 + 1;
            aw[jp] = pack2bf(xt[k0 % 20] * tv[k0 / 20],
                             xt[k1 % 20] * tv[k1 / 20]);
        }
        const bf16x8 a = __builtin_bit_cast(bf16x8, aw);
        #pragma unroll
        for (int nt = 0; nt < 5; ++nt) {
            bf16x8 b = *(const bf16x8*)(wb[nt] + 8 * ks);
            acc[nt] = __builtin_amdgcn_mfma_f32_16x16x32_bf16(a, b, acc[nt], 0, 0, 0);
        }
    }

    // Scatter: C/D row = 4*quad + r -> edge e0+4*quad+r (dst read directly,
    // 4 lanes/addr broadcast, L1-hot); col = lrow -> op = 16*nt + lrow.
    #pragma unroll
    for (int r = 0; r < 4; ++r) {
        const int d = ei[2 * (e0 + 4 * quad + r) + 1];
        float* yd = y + (size_t)d * OP + lrow;
        #pragma unroll
        for (int nt = 0; nt < 5; ++nt)
            atomicAdd(yd + 16 * nt, acc[nt][r]);
    }
}

// ---------------------------------------------------------------------------
// Regular nonlinearity (+ optional residual). One thread per (n,c).
// ---------------------------------------------------------------------------
__global__ void nonlin(const float* __restrict__ yin, const float* __restrict__ res,
                       float* __restrict__ out) {
    int idx = blockIdx.x * blockDim.x + threadIdx.x;  // over N*C
    if (idx >= NN * NC) return;
    const float* vp = yin + (long long)idx * NQ;
    float a0 = vp[0], a1 = vp[1], a2 = vp[2], a3 = vp[3], a4 = vp[4];
    if (res != nullptr) {
        const float* rp = res + (long long)idx * NQ;
        a0 += rp[0]; a1 += rp[1]; a2 += rp[2]; a3 += rp[3]; a4 += rp[4];
    }
    float o0 = 0.f, o1 = 0.f, o2 = 0.f, o3 = 0.f, o4 = 0.f;
    #pragma unroll
    for (int k = 0; k < 7; ++k) {
        float th = (float)(2.0 * M_PI / 7.0) * (float)k;
        float c1k = cosf(th), s1k = sinf(th);
        float c2k = cosf(2.0f * th), s2k = sinf(2.0f * th);
        float s = a0 + a1 * c1k + a2 * s1k + a3 * c2k + a4 * s2k;
        s = fmaxf(s, 0.0f);
        o0 += s;
        o1 += s * c1k; o2 += s * s1k;
        o3 += s * c2k; o4 += s * s2k;
    }
    const float i7 = 1.0f / 7.0f, t7 = 2.0f / 7.0f;
    float* op = out + (long long)idx * NQ;
    op[0] = o0 * i7;
    op[1] = o1 * t7; op[2] = o2 * t7;
    op[3] = o3 * t7; op[4] = o4 * t7;
}

// ---------------------------------------------------------------------------
extern "C" void kernel_launch(void* const* d_in, const int* in_sizes, int n_in,
                              void* d_out, int out_size, void* d_ws, size_t ws_size,
                              hipStream_t stream) {
    const float* x    = (const float*)d_in[0];
    const int*   ei   = (const int*)d_in[1];      // int inputs arrive as int32
    const float* pre  = (const float*)d_in[2];
    const float* phi  = (const float*)d_in[3];
    const float* W1   = (const float*)d_in[4];
    const float* b1   = (const float*)d_in[5];
    const float* Ws1  = (const float*)d_in[6];
    const float* W2   = (const float*)d_in[7];
    const float* b2   = (const float*)d_in[8];
    const float* Ws2  = (const float*)d_in[9];
    float* out = (float*)d_out;

    // Workspace layout
    unsigned short* Wt1 = (unsigned short*)d_ws;          // 64000 bf16 = 128 KB
    unsigned short* Wt2 = Wt1 + WSZ;                      // 128 KB
    float* y1 = (float*)(Wt2 + WSZ);                      // 800000 f (3.2 MB)
    float* h  = y1 + (size_t)NN * OP;                     // 800000 f (3.2 MB)

    reorder_wt<<<(WSZ + 255) / 256, 256, 0, stream>>>(W1, W2, Wt1, Wt2);

    // Layer 1
    selfint<<<(NN * OP + 255) / 256, 256, 0, stream>>>(x, Ws1, b1, y1);
    edge_conv_mfma<<<NE / 16, 64, 0, stream>>>(x, ei, pre, phi, Wt1, y1);
    nonlin<<<(NN * NC + 255) / 256, 256, 0, stream>>>(y1, nullptr, h);

    // Layer 2 (reuse y1)
    selfint<<<(NN * OP + 255) / 256, 256, 0, stream>>>(h, Ws2, b2, y1);
    edge_conv_mfma<<<NE / 16, 64, 0, stream>>>(h, ei, pre, phi, Wt2, y1);

    // Residual + final nonlinearity -> d_out
    nonlin<<<(NN * NC + 255) / 256, 256, 0, stream>>>(y1, x, out);
}

// Round 10
// 284.781 us; speedup vs baseline: 1.6459x; 1.6459x over previous
//
#include <hip/hip_runtime.h>
#include <hip/hip_bf16.h>
#include <hip/hip_fp16.h>
#include <math.h>

#ifndef M_PI
#define M_PI 3.14159265358979323846
#endif

// Problem constants
#define NN 10000      // nodes
#define NE 160000     // edges
#define NC 16         // channels
#define NQ 5          // 2*order+1
#define NFR 10        // N_FREQ * N_RINGS
#define CQ 80         // NC*NQ (K per fr)
#define OP 80         // outputs per node
#define KTOT 800      // GEMM K
#define WSZ 64000     // 80*800 weight elements

#define MT 32         // edges per block in edge GEMM
#define AS_STRIDE 808 // A_s row stride in fp16 elems (800 + 8 pad; 1616 B)

typedef __attribute__((ext_vector_type(8))) _Float16 f16x8;
typedef __attribute__((ext_vector_type(4))) float f32x4;

// RNE float->fp16 (values well within fp16 range: |A|<~500, |W|<~0.5)
static __device__ __forceinline__ unsigned short f2h_u(float f) {
    return __builtin_bit_cast(unsigned short, (_Float16)f);
}
static __device__ __forceinline__ unsigned pack2h(float lo, float hi) {
    return (unsigned)f2h_u(lo) | ((unsigned)f2h_u(hi) << 16);
}

// ---------------------------------------------------------------------------
// Reorder + convert W into MFMA-B FRAGMENT ORDER with NATURAL k (R5's k map):
//   Wt_frag[((ks*5+nt)*64 + lane)*8 + j] = fp16( W at n=16*nt+lrow,
//                                                k = 32*ks + 8*quad + j )
//   k decodes naturally: fr = k/80, cq = k%80  (exactly R5's layout).
// By construction each table slot holds exactly the value the verified R5
// kernel loaded for that (ks,nt,lane,j) slot — value-identical GEMM, only
// the address pattern changes (64-line scatter -> coalesced lane*16B).
// ---------------------------------------------------------------------------
__global__ void reorder_wt(const float* __restrict__ W1, const float* __restrict__ W2,
                           unsigned short* __restrict__ Wt1, unsigned short* __restrict__ Wt2) {
    int i = blockIdx.x * blockDim.x + threadIdx.x;  // over 64000
    if (i >= WSZ) return;
    int j    = i & 7;
    int lane = (i >> 3) & 63;
    int grp  = i >> 9;           // 0..124 = ks*5 + nt
    int ks   = grp / 5;
    int nt   = grp % 5;
    int quad = lane >> 4;
    int lrow = lane & 15;
    int n    = 16 * nt + lrow;
    int k    = 32 * ks + 8 * quad + j;   // natural k (R5)
    int fr = k / CQ, cq = k % CQ;
    int c = cq / NQ, q = cq % NQ;
    int f = fr / 2,  r = fr % 2;
    int o = n / NQ,  p = n % NQ;
    int src = ((((o * NC + c) * NQ + p) * NQ + q) * 5 + f) * 2 + r;
    Wt1[i] = f2h_u(W1[src]);
    Wt2[i] = f2h_u(W2[src]);
}

// ---------------------------------------------------------------------------
// Self-interaction + bias (fp32): y[n,op] = sum_cq x[n,cq]*Ws[o,c,p,q] + (p==0)b[o]
// Full write — serves as init before edge atomics.
// ---------------------------------------------------------------------------
__global__ void selfint(const float* __restrict__ xin, const float* __restrict__ Ws,
                        const float* __restrict__ b, float* __restrict__ y) {
    __shared__ float ws_s[NC * NC * NQ * NQ];  // 25.6 KB
    int tid = threadIdx.x;
    for (int i = tid; i < NC * NC * NQ * NQ; i += blockDim.x) ws_s[i] = Ws[i];
    __syncthreads();
    int idx = blockIdx.x * blockDim.x + tid;     // over N*80
    if (idx >= NN * OP) return;
    int n = idx / OP, op = idx % OP;
    int o = op / NQ, p = op % NQ;
    const float* xrow = xin + n * CQ;
    float acc = (p == 0) ? b[o] : 0.0f;
    #pragma unroll
    for (int c = 0; c < NC; ++c)
        #pragma unroll
        for (int q = 0; q < NQ; ++q)
            acc = fmaf(xrow[c * NQ + q], ws_s[o * 400 + c * 25 + p * 5 + q], acc);
    y[idx] = acc;
}

// ---------------------------------------------------------------------------
// Edge conv: EXACT R5 structure (verified absmax 1.0), fp16 + frag-ordered B.
// Block = 128 threads (2 waves), 32 edges.
// Phase 1: 4 threads/edge gather x[src] (20 floats each), transport, scale
//   by t[e,fr], pack fp16 into A_s[32][800] (natural k = fr*80+cq, padded).
// Phase 2: wave w -> edge rows 16w..16w+15; 25 K-steps x 5 n-tiles of
//   v_mfma_f32_16x16x32_f16. A-frag: ds_read_b128 at 32*ks+8*quad (R5 map);
//   B-frag: wf[(ks*5+nt)*64+lane] — coalesced, sequential, L2-hot 128 KB.
// Phase 3: atomic scatter to y[dst] via dst_s.
// ---------------------------------------------------------------------------
__global__ __launch_bounds__(128)
void edge_conv_mfma(const float* __restrict__ xin, const int* __restrict__ ei,
                    const float* __restrict__ pre, const float* __restrict__ phi_arr,
                    const unsigned short* __restrict__ Wt, float* __restrict__ y) {
    __shared__ __align__(16) unsigned short A_s[MT * AS_STRIDE];  // 51,712 B
    __shared__ int dst_s[MT];

    const int tid = threadIdx.x;
    const int e0 = blockIdx.x * MT;     // NE = 5000 * 32 exactly

    // ---- Phase 1: build A tile ----
    const int el = tid >> 2;            // local edge 0..31
    const int q4 = tid & 3;             // cq quarter [20*q4, 20*q4+20)
    const int e  = e0 + el;
    const int src = ei[2 * e];
    if (q4 == 0) dst_s[el] = ei[2 * e + 1];

    float s1, c1;
    sincosf(phi_arr[e], &s1, &c1);
    const float c2 = c1 * c1 - s1 * s1;
    const float s2 = 2.0f * c1 * s1;

    float xt[20];
    const float4* xp = (const float4*)(xin + (size_t)src * CQ + 20 * q4);
    #pragma unroll
    for (int k4 = 0; k4 < 5; ++k4) {
        float4 v = xp[k4];
        xt[4 * k4 + 0] = v.x; xt[4 * k4 + 1] = v.y;
        xt[4 * k4 + 2] = v.z; xt[4 * k4 + 3] = v.w;
    }
    #pragma unroll
    for (int cc = 0; cc < 4; ++cc) {    // 4 channels, rotate (1,2) and (3,4)
        float a1 = xt[cc * 5 + 1], b1 = xt[cc * 5 + 2];
        float a2 = xt[cc * 5 + 3], b2 = xt[cc * 5 + 4];
        xt[cc * 5 + 1] = c1 * a1 - s1 * b1;
        xt[cc * 5 + 2] = s1 * a1 + c1 * b1;
        xt[cc * 5 + 3] = c2 * a2 - s2 * b2;
        xt[cc * 5 + 4] = s2 * a2 + c2 * b2;
    }
    float tv[NFR];
    #pragma unroll
    for (int fr = 0; fr < NFR; ++fr) tv[fr] = pre[(size_t)e * NFR + fr];

    #pragma unroll
    for (int fr = 0; fr < NFR; ++fr) {
        const float tf = tv[fr];
        uint2* dp = (uint2*)&A_s[el * AS_STRIDE + fr * CQ + 20 * q4]; // 8B-aligned
        #pragma unroll
        for (int j = 0; j < 5; ++j) {
            unsigned lo = pack2h(xt[4 * j + 0] * tf, xt[4 * j + 1] * tf);
            unsigned hi = pack2h(xt[4 * j + 2] * tf, xt[4 * j + 3] * tf);
            dp[j] = make_uint2(lo, hi);
        }
    }
    __syncthreads();

    // ---- Phase 2: GEMM ----
    const int wave = tid >> 6;          // 0..1 -> m-tile
    const int lane = tid & 63;
    const int lrow = lane & 15;
    const int quad = lane >> 4;
    const int m0 = 16 * wave;

    f32x4 acc[5];
    #pragma unroll
    for (int nt = 0; nt < 5; ++nt) acc[nt] = (f32x4){0.f, 0.f, 0.f, 0.f};

    const f16x8* __restrict__ wf = (const f16x8*)Wt;
    const unsigned short* As_row = &A_s[(m0 + lrow) * AS_STRIDE];
    #pragma unroll 1
    for (int ks = 0; ks < 25; ++ks) {
        f16x8 a = *(const f16x8*)(As_row + 32 * ks + 8 * quad);
        #pragma unroll
        for (int nt = 0; nt < 5; ++nt) {
            f16x8 b = wf[(ks * 5 + nt) * 64 + lane];
            acc[nt] = __builtin_amdgcn_mfma_f32_16x16x32_f16(a, b, acc[nt], 0, 0, 0);
        }
    }

    // ---- Phase 3: scatter ----
    #pragma unroll
    for (int nt = 0; nt < 5; ++nt) {
        #pragma unroll
        for (int r = 0; r < 4; ++r) {
            int erow = m0 + quad * 4 + r;          // local edge row
            int op = 16 * nt + lrow;
            atomicAdd(y + (size_t)dst_s[erow] * OP + op, acc[nt][r]);
        }
    }
}

// ---------------------------------------------------------------------------
// Regular nonlinearity (+ optional residual). One thread per (n,c).
// ---------------------------------------------------------------------------
__global__ void nonlin(const float* __restrict__ yin, const float* __restrict__ res,
                       float* __restrict__ out) {
    int idx = blockIdx.x * blockDim.x + threadIdx.x;  // over N*C
    if (idx >= NN * NC) return;
    const float* vp = yin + (long long)idx * NQ;
    float a0 = vp[0], a1 = vp[1], a2 = vp[2], a3 = vp[3], a4 = vp[4];
    if (res != nullptr) {
        const float* rp = res + (long long)idx * NQ;
        a0 += rp[0]; a1 += rp[1]; a2 += rp[2]; a3 += rp[3]; a4 += rp[4];
    }
    float o0 = 0.f, o1 = 0.f, o2 = 0.f, o3 = 0.f, o4 = 0.f;
    #pragma unroll
    for (int k = 0; k < 7; ++k) {
        float th = (float)(2.0 * M_PI / 7.0) * (float)k;
        float c1k = cosf(th), s1k = sinf(th);
        float c2k = cosf(2.0f * th), s2k = sinf(2.0f * th);
        float s = a0 + a1 * c1k + a2 * s1k + a3 * c2k + a4 * s2k;
        s = fmaxf(s, 0.0f);
        o0 += s;
        o1 += s * c1k; o2 += s * s1k;
        o3 += s * c2k; o4 += s * s2k;
    }
    const float i7 = 1.0f / 7.0f, t7 = 2.0f / 7.0f;
    float* op = out + (long long)idx * NQ;
    op[0] = o0 * i7;
    op[1] = o1 * t7; op[2] = o2 * t7;
    op[3] = o3 * t7; op[4] = o4 * t7;
}

// ---------------------------------------------------------------------------
extern "C" void kernel_launch(void* const* d_in, const int* in_sizes, int n_in,
                              void* d_out, int out_size, void* d_ws, size_t ws_size,
                              hipStream_t stream) {
    const float* x    = (const float*)d_in[0];
    const int*   ei   = (const int*)d_in[1];      // int inputs arrive as int32
    const float* pre  = (const float*)d_in[2];
    const float* phi  = (const float*)d_in[3];
    const float* W1   = (const float*)d_in[4];
    const float* b1   = (const float*)d_in[5];
    const float* Ws1  = (const float*)d_in[6];
    const float* W2   = (const float*)d_in[7];
    const float* b2   = (const float*)d_in[8];
    const float* Ws2  = (const float*)d_in[9];
    float* out = (float*)d_out;

    // Workspace layout
    unsigned short* Wt1 = (unsigned short*)d_ws;          // 64000 fp16 = 128 KB
    unsigned short* Wt2 = Wt1 + WSZ;                      // 128 KB
    float* y1 = (float*)(Wt2 + WSZ);                      // 800000 f (3.2 MB)
    float* h  = y1 + (size_t)NN * OP;                     // 800000 f (3.2 MB)

    reorder_wt<<<(WSZ + 255) / 256, 256, 0, stream>>>(W1, W2, Wt1, Wt2);

    // Layer 1
    selfint<<<(NN * OP + 255) / 256, 256, 0, stream>>>(x, Ws1, b1, y1);
    edge_conv_mfma<<<NE / MT, 128, 0, stream>>>(x, ei, pre, phi, Wt1, y1);
    nonlin<<<(NN * NC + 255) / 256, 256, 0, stream>>>(y1, nullptr, h);

    // Layer 2 (reuse y1)
    selfint<<<(NN * OP + 255) / 256, 256, 0, stream>>>(h, Ws2, b2, y1);
    edge_conv_mfma<<<NE / MT, 128, 0, stream>>>(h, ei, pre, phi, Wt2, y1);

    // Residual + final nonlinearity -> d_out
    nonlin<<<(NN * NC + 255) / 256, 256, 0, stream>>>(y1, x, out);
}

// Round 11
// 279.606 us; speedup vs baseline: 1.6764x; 1.0185x over previous
//
#include <hip/hip_runtime.h>
#include <hip/hip_bf16.h>
#include <hip/hip_fp16.h>
#include <math.h>

#ifndef M_PI
#define M_PI 3.14159265358979323846
#endif

// Problem constants
#define NN 10000      // nodes
#define NE 160000     // edges
#define NC 16         // channels
#define NQ 5          // 2*order+1
#define NFR 10        // N_FREQ * N_RINGS
#define CQ 80         // NC*NQ (K per fr)
#define OP 80         // outputs per node
#define KTOT 800      // GEMM K
#define WSZ 64000     // 80*800 weight elements

#define MT 32         // edges per block in edge GEMM
#define CSTRIDE 168   // chunk row stride in fp16 elems (160 + 8 pad; 336 B, 16B-aligned)

typedef __attribute__((ext_vector_type(8))) _Float16 f16x8;
typedef __attribute__((ext_vector_type(4))) float f32x4;

// RNE float->fp16 (values well within fp16 range: |A|<~500, |W|<~0.5)
static __device__ __forceinline__ unsigned short f2h_u(float f) {
    return __builtin_bit_cast(unsigned short, (_Float16)f);
}
static __device__ __forceinline__ unsigned pack2h(float lo, float hi) {
    return (unsigned)f2h_u(lo) | ((unsigned)f2h_u(hi) << 16);
}

// ---------------------------------------------------------------------------
// Reorder + convert W into MFMA-B FRAGMENT ORDER with NATURAL k (R5's k map):
//   Wt_frag[((ks*5+nt)*64 + lane)*8 + j] = fp16( W at n=16*nt+lrow,
//                                                k = 32*ks + 8*quad + j )
//   k decodes naturally: fr = k/80, cq = k%80  (exactly R5's layout).
// Verified R10: value-identical GEMM, coalesced lane*16B B-loads.
// ---------------------------------------------------------------------------
__global__ void reorder_wt(const float* __restrict__ W1, const float* __restrict__ W2,
                           unsigned short* __restrict__ Wt1, unsigned short* __restrict__ Wt2) {
    int i = blockIdx.x * blockDim.x + threadIdx.x;  // over 64000
    if (i >= WSZ) return;
    int j    = i & 7;
    int lane = (i >> 3) & 63;
    int grp  = i >> 9;           // 0..124 = ks*5 + nt
    int ks   = grp / 5;
    int nt   = grp % 5;
    int quad = lane >> 4;
    int lrow = lane & 15;
    int n    = 16 * nt + lrow;
    int k    = 32 * ks + 8 * quad + j;   // natural k (R5)
    int fr = k / CQ, cq = k % CQ;
    int c = cq / NQ, q = cq % NQ;
    int f = fr / 2,  r = fr % 2;
    int o = n / NQ,  p = n % NQ;
    int src = ((((o * NC + c) * NQ + p) * NQ + q) * 5 + f) * 2 + r;
    Wt1[i] = f2h_u(W1[src]);
    Wt2[i] = f2h_u(W2[src]);
}

// ---------------------------------------------------------------------------
// Self-interaction + bias (fp32): y[n,op] = sum_cq x[n,cq]*Ws[o,c,p,q] + (p==0)b[o]
// Full write — serves as init before edge atomics.
// ---------------------------------------------------------------------------
__global__ void selfint(const float* __restrict__ xin, const float* __restrict__ Ws,
                        const float* __restrict__ b, float* __restrict__ y) {
    __shared__ float ws_s[NC * NC * NQ * NQ];  // 25.6 KB
    int tid = threadIdx.x;
    for (int i = tid; i < NC * NC * NQ * NQ; i += blockDim.x) ws_s[i] = Ws[i];
    __syncthreads();
    int idx = blockIdx.x * blockDim.x + tid;     // over N*80
    if (idx >= NN * OP) return;
    int n = idx / OP, op = idx % OP;
    int o = op / NQ, p = op % NQ;
    const float* xrow = xin + n * CQ;
    float acc = (p == 0) ? b[o] : 0.0f;
    #pragma unroll
    for (int c = 0; c < NC; ++c)
        #pragma unroll
        for (int q = 0; q < NQ; ++q)
            acc = fmaf(xrow[c * NQ + q], ws_s[o * 400 + c * 25 + p * 5 + q], acc);
    y[idx] = acc;
}

// ---------------------------------------------------------------------------
// Edge conv v10: R10's verified kernel with K-CHUNKED A staging.
// R10 profile: occupancy 14.9% (52 KB A_s -> 3 blocks/CU), latency-bound
// (VALUBusy 29%, MfmaUtil 9%). Fix: stage K in 5 chunks of 160 (=2 fr),
// A_s[32][168] = 10.75 KB single buffer, barrier / 5 ks-steps / barrier per
// chunk. Same values, same ks order -> bit-identical MFMA accumulation.
// Chunk loop fully unrolled so tv[] indices stay compile-time (no dynamic-
// index scratch spill). xt/tv live in registers across chunks.
// Occupancy becomes VGPR-capped (~88 VGPR -> 5 waves/SIMD, 10 blocks/CU).
// ---------------------------------------------------------------------------
__global__ __launch_bounds__(128)
void edge_conv_mfma(const float* __restrict__ xin, const int* __restrict__ ei,
                    const float* __restrict__ pre, const float* __restrict__ phi_arr,
                    const unsigned short* __restrict__ Wt, float* __restrict__ y) {
    __shared__ __align__(16) unsigned short A_s[MT * CSTRIDE];  // 10,752 B
    __shared__ int dst_s[MT];

    const int tid = threadIdx.x;
    const int e0 = blockIdx.x * MT;     // NE = 5000 * 32 exactly

    // ---- per-edge prep: 4 threads/edge, quarter q4 of cq ----
    const int el = tid >> 2;            // local edge 0..31
    const int q4 = tid & 3;             // cq quarter [20*q4, 20*q4+20)
    const int e  = e0 + el;
    const int src = ei[2 * e];
    if (q4 == 0) dst_s[el] = ei[2 * e + 1];

    float s1, c1;
    sincosf(phi_arr[e], &s1, &c1);
    const float c2 = c1 * c1 - s1 * s1;
    const float s2 = 2.0f * c1 * s1;

    float xt[20];
    const float4* xp = (const float4*)(xin + (size_t)src * CQ + 20 * q4);
    #pragma unroll
    for (int k4 = 0; k4 < 5; ++k4) {
        float4 v = xp[k4];
        xt[4 * k4 + 0] = v.x; xt[4 * k4 + 1] = v.y;
        xt[4 * k4 + 2] = v.z; xt[4 * k4 + 3] = v.w;
    }
    #pragma unroll
    for (int cc = 0; cc < 4; ++cc) {    // 4 channels, rotate (1,2) and (3,4)
        float a1 = xt[cc * 5 + 1], b1 = xt[cc * 5 + 2];
        float a2 = xt[cc * 5 + 3], b2 = xt[cc * 5 + 4];
        xt[cc * 5 + 1] = c1 * a1 - s1 * b1;
        xt[cc * 5 + 2] = s1 * a1 + c1 * b1;
        xt[cc * 5 + 3] = c2 * a2 - s2 * b2;
        xt[cc * 5 + 4] = s2 * a2 + c2 * b2;
    }
    float tv[NFR];
    #pragma unroll
    for (int fr = 0; fr < NFR; ++fr) tv[fr] = pre[(size_t)e * NFR + fr];

    // ---- GEMM lane mapping ----
    const int wave = tid >> 6;          // 0..1 -> m-tile
    const int lane = tid & 63;
    const int lrow = lane & 15;
    const int quad = lane >> 4;
    const int m0 = 16 * wave;

    f32x4 acc[5];
    #pragma unroll
    for (int nt = 0; nt < 5; ++nt) acc[nt] = (f32x4){0.f, 0.f, 0.f, 0.f};

    const f16x8* __restrict__ wf = (const f16x8*)Wt;
    const unsigned short* As_row = &A_s[(m0 + lrow) * CSTRIDE];

    #pragma unroll
    for (int ch = 0; ch < 5; ++ch) {
        // stage chunk ch: fr = 2ch, 2ch+1  (k-window [160*ch, 160*ch+160))
        #pragma unroll
        for (int frl = 0; frl < 2; ++frl) {
            const float tf = tv[2 * ch + frl];
            uint2* dp = (uint2*)&A_s[el * CSTRIDE + frl * CQ + 20 * q4]; // 8B-aligned
            #pragma unroll
            for (int j = 0; j < 5; ++j) {
                unsigned lo = pack2h(xt[4 * j + 0] * tf, xt[4 * j + 1] * tf);
                unsigned hi = pack2h(xt[4 * j + 2] * tf, xt[4 * j + 3] * tf);
                dp[j] = make_uint2(lo, hi);
            }
        }
        __syncthreads();

        // consume chunk: global ks = 5*ch + s, local k offset 32*s
        #pragma unroll
        for (int s = 0; s < 5; ++s) {
            f16x8 a = *(const f16x8*)(As_row + 32 * s + 8 * quad);
            #pragma unroll
            for (int nt = 0; nt < 5; ++nt) {
                f16x8 b = wf[((5 * ch + s) * 5 + nt) * 64 + lane];
                acc[nt] = __builtin_amdgcn_mfma_f32_16x16x32_f16(a, b, acc[nt], 0, 0, 0);
            }
        }
        __syncthreads();   // protect A_s before next chunk's overwrite
    }

    // ---- scatter ----
    #pragma unroll
    for (int nt = 0; nt < 5; ++nt) {
        #pragma unroll
        for (int r = 0; r < 4; ++r) {
            int erow = m0 + quad * 4 + r;          // local edge row
            int op = 16 * nt + lrow;
            atomicAdd(y + (size_t)dst_s[erow] * OP + op, acc[nt][r]);
        }
    }
}

// ---------------------------------------------------------------------------
// Regular nonlinearity (+ optional residual). One thread per (n,c).
// ---------------------------------------------------------------------------
__global__ void nonlin(const float* __restrict__ yin, const float* __restrict__ res,
                       float* __restrict__ out) {
    int idx = blockIdx.x * blockDim.x + threadIdx.x;  // over N*C
    if (idx >= NN * NC) return;
    const float* vp = yin + (long long)idx * NQ;
    float a0 = vp[0], a1 = vp[1], a2 = vp[2], a3 = vp[3], a4 = vp[4];
    if (res != nullptr) {
        const float* rp = res + (long long)idx * NQ;
        a0 += rp[0]; a1 += rp[1]; a2 += rp[2]; a3 += rp[3]; a4 += rp[4];
    }
    float o0 = 0.f, o1 = 0.f, o2 = 0.f, o3 = 0.f, o4 = 0.f;
    #pragma unroll
    for (int k = 0; k < 7; ++k) {
        float th = (float)(2.0 * M_PI / 7.0) * (float)k;
        float c1k = cosf(th), s1k = sinf(th);
        float c2k = cosf(2.0f * th), s2k = sinf(2.0f * th);
        float s = a0 + a1 * c1k + a2 * s1k + a3 * c2k + a4 * s2k;
        s = fmaxf(s, 0.0f);
        o0 += s;
        o1 += s * c1k; o2 += s * s1k;
        o3 += s * c2k; o4 += s * s2k;
    }
    const float i7 = 1.0f / 7.0f, t7 = 2.0f / 7.0f;
    float* op = out + (long long)idx * NQ;
    op[0] = o0 * i7;
    op[1] = o1 * t7; op[2] = o2 * t7;
    op[3] = o3 * t7; op[4] = o4 * t7;
}

// ---------------------------------------------------------------------------
extern "C" void kernel_launch(void* const* d_in, const int* in_sizes, int n_in,
                              void* d_out, int out_size, void* d_ws, size_t ws_size,
                              hipStream_t stream) {
    const float* x    = (const float*)d_in[0];
    const int*   ei   = (const int*)d_in[1];      // int inputs arrive as int32
    const float* pre  = (const float*)d_in[2];
    const float* phi  = (const float*)d_in[3];
    const float* W1   = (const float*)d_in[4];
    const float* b1   = (const float*)d_in[5];
    const float* Ws1  = (const float*)d_in[6];
    const float* W2   = (const float*)d_in[7];
    const float* b2   = (const float*)d_in[8];
    const float* Ws2  = (const float*)d_in[9];
    float* out = (float*)d_out;

    // Workspace layout
    unsigned short* Wt1 = (unsigned short*)d_ws;          // 64000 fp16 = 128 KB
    unsigned short* Wt2 = Wt1 + WSZ;                      // 128 KB
    float* y1 = (float*)(Wt2 + WSZ);                      // 800000 f (3.2 MB)
    float* h  = y1 + (size_t)NN * OP;                     // 800000 f (3.2 MB)

    reorder_wt<<<(WSZ + 255) / 256, 256, 0, stream>>>(W1, W2, Wt1, Wt2);

    // Layer 1
    selfint<<<(NN * OP + 255) / 256, 256, 0, stream>>>(x, Ws1, b1, y1);
    edge_conv_mfma<<<NE / MT, 128, 0, stream>>>(x, ei, pre, phi, Wt1, y1);
    nonlin<<<(NN * NC + 255) / 256, 256, 0, stream>>>(y1, nullptr, h);

    // Layer 2 (reuse y1)
    selfint<<<(NN * OP + 255) / 256, 256, 0, stream>>>(h, Ws2, b2, y1);
    edge_conv_mfma<<<NE / MT, 128, 0, stream>>>(h, ei, pre, phi, Wt2, y1);

    // Residual + final nonlinearity -> d_out
    nonlin<<<(NN * NC + 255) / 256, 256, 0, stream>>>(y1, x, out);
}